// Round 9
// baseline (106.052 us; speedup 1.0000x reference)
//
#include <hip/hip_runtime.h>

#define N_NODES 100000
#define N_EDGES 1000000
#define D_FEAT  64

// Binning: 32 consecutive dst nodes per bin; 3125*32 == 100000 exactly.
#define BIN_SHIFT 5
#define BIN_NODES 32
#define NBINS 3125
#define BIN_CAP 768          // == NREP*REP_CAP, LDS staging capacity per bin

// Replicated bucket cursors: 8 replicas per bin (replica = blockIdx & 7 ->
// same XCD under round-robin dispatch). Mean edges per (bin,replica) = 40;
// REP_CAP 96 is ~9 sigma headroom (Poisson(40)).
#define NREP 8
#define REP_CAP 96
#define NB_SCAT 256
#define CHUNK2 ((N_EDGES + NB_SCAT - 1) / NB_SCAT)   // 3907

// ---------------------------------------------------------------------------
// Workspace layout (ints):
//   cur    [NBINS*NREP]          per-(bin,replica) slot counters
//   bucket [NBINS*NREP*REP_CAP]  packed (local_dst << 17) | src
// total ~9.7 MB
// ---------------------------------------------------------------------------
#define WS_CUR    0
#define WS_BUCKET (NBINS * NREP)
#define WS_NEEDED ((size_t)(NBINS * NREP + NBINS * NREP * REP_CAP) * sizeof(int))

// K1: zero the cursors
__global__ __launch_bounds__(1024) void cur_zero_kernel(int* __restrict__ ws) {
    int i = blockIdx.x * 1024 + threadIdx.x;
    if (i < NBINS * NREP) ws[WS_CUR + i] = 0;
}

// K2: bucket scatter via replicated cursors. Chain length per cursor ~40;
// consecutive chain winners get adjacent slots -> line-clustered writes;
// replica = blockIdx&7 keeps each cursor's writers on one XCD.
__global__ __launch_bounds__(1024) void rep_scatter_kernel(const int* __restrict__ src,
                                                           const int* __restrict__ dst,
                                                           int* __restrict__ ws) {
    int blk = blockIdx.x;
    int r   = blk & (NREP - 1);
    int e0 = blk * CHUNK2, e1 = min(N_EDGES, e0 + CHUNK2);
    for (int e = e0 + threadIdx.x; e < e1; e += 1024) {
        int d = dst[e], s = src[e];
        int b = d >> BIN_SHIFT;
        int idx = atomicAdd(&ws[WS_CUR + b * NREP + r], 1);
        if (idx < REP_CAP)   // statistically never false; defensive
            ws[WS_BUCKET + (b * NREP + r) * REP_CAP + idx] =
                ((d & (BIN_NODES - 1)) << 17) | s;
    }
}

// K3: per-bin: concatenate 8 replica regions into LDS (+histogram),
// counting-sort by local dst, then float4 gather with 16-lane-per-row loads
// and a 2-step shfl_xor reduce across 4 edge subgroups (R7's proven variant).
__global__ __launch_bounds__(256) void fused_gather_kernel(const float* __restrict__ emb,
                                                           const int* __restrict__ ws,
                                                           float* __restrict__ out) {
    __shared__ int s_edges[BIN_CAP];
    __shared__ int s_sorted[BIN_CAP];
    __shared__ int s_hist[BIN_NODES];
    __shared__ int s_off[BIN_NODES];
    __shared__ int s_cur[BIN_NODES];
    __shared__ int s_roff[NREP];
    __shared__ int s_rct[NREP];

    int b   = blockIdx.x;
    int tid = threadIdx.x;

    if (tid < BIN_NODES) s_hist[tid] = 0;
    if (tid == 0) {
        int acc = 0;
        #pragma unroll
        for (int r = 0; r < NREP; ++r) {
            int c = ws[WS_CUR + b * NREP + r];
            c = min(c, REP_CAP);
            s_roff[r] = acc;
            s_rct[r]  = c;
            acc += c;
        }
    }
    __syncthreads();

    // load: 8 subgroups of 32 lanes, one replica region each
    {
        int sg = tid >> 5, li = tid & 31;
        int c = s_rct[sg], o = s_roff[sg];
        const int* __restrict__ reg = ws + WS_BUCKET + (b * NREP + sg) * REP_CAP;
        for (int i = li; i < c; i += 32) {
            int p = reg[i];
            s_edges[o + i] = p;
            atomicAdd(&s_hist[p >> 17], 1);
        }
    }
    __syncthreads();
    int cnt = s_roff[NREP - 1] + s_rct[NREP - 1];

    // scan 32 hist entries with the first 32 lanes
    if (tid < 32) {
        int v = s_hist[tid];
        int incl = v;
        #pragma unroll
        for (int o = 1; o < 32; o <<= 1) {
            int t = __shfl_up(incl, o);
            if (tid >= o) incl += t;
        }
        s_off[tid] = incl - v;
        s_cur[tid] = incl - v;
    }
    __syncthreads();

    // counting-sort scatter within LDS
    for (int i = tid; i < cnt; i += 256) {
        int p = s_edges[i];
        int slot = atomicAdd(&s_cur[p >> 17], 1);
        s_sorted[slot] = p & 0x1FFFF;
    }
    __syncthreads();

    // gather: 4 waves x 8 nodes; sub = edge slot (0..3), fq = float4 index
    int wave = tid >> 6, lane = tid & 63;
    int sub  = lane >> 4;
    int fq   = lane & 15;

    for (int ln = wave * 8; ln < wave * 8 + 8; ++ln) {
        int deg = s_hist[ln];
        int off = s_off[ln];

        float4 acc = make_float4(0.f, 0.f, 0.f, 0.f);
        int i = sub;
        for (; i + 4 < deg; i += 8) {
            int s0 = s_sorted[off + i];
            int s1 = s_sorted[off + i + 4];
            const float4* r0 = (const float4*)(emb + (size_t)s0 * D_FEAT);
            const float4* r1 = (const float4*)(emb + (size_t)s1 * D_FEAT);
            float4 v0 = r0[fq];
            float4 v1 = r1[fq];
            acc.x += v0.x + v1.x;
            acc.y += v0.y + v1.y;
            acc.z += v0.z + v1.z;
            acc.w += v0.w + v1.w;
        }
        if (i < deg) {
            int s0 = s_sorted[off + i];
            const float4* r0 = (const float4*)(emb + (size_t)s0 * D_FEAT);
            float4 v0 = r0[fq];
            acc.x += v0.x; acc.y += v0.y; acc.z += v0.z; acc.w += v0.w;
        }

        #pragma unroll
        for (int m = 16; m < 64; m <<= 1) {
            acc.x += __shfl_xor(acc.x, m);
            acc.y += __shfl_xor(acc.y, m);
            acc.z += __shfl_xor(acc.z, m);
            acc.w += __shfl_xor(acc.w, m);
        }

        if (sub == 0) {
            int node = (b << BIN_SHIFT) + ln;   // < N_NODES (3125*32 exact)
            float inv = 1.0f / (float)max(deg, 1);
            acc.x *= inv; acc.y *= inv; acc.z *= inv; acc.w *= inv;
            *(float4*)(out + (size_t)node * D_FEAT + fq * 4) = acc;
        }
    }
}

// ======================= Fallback (R1 atomic path) =========================

__global__ void gcn_zero_kernel(float* __restrict__ out, float* __restrict__ counts) {
    int stride = gridDim.x * blockDim.x;
    int i = blockIdx.x * blockDim.x + threadIdx.x;
    const int total = N_NODES * D_FEAT;
    for (int idx = i; idx < total; idx += stride) out[idx] = 0.0f;
    for (int idx = i; idx < N_NODES; idx += stride) counts[idx] = 0.0f;
}

__global__ void gcn_scatter_kernel(const float* __restrict__ emb,
                                   const int* __restrict__ src,
                                   const int* __restrict__ dst,
                                   float* __restrict__ out,
                                   float* __restrict__ counts) {
    int gid  = blockIdx.x * blockDim.x + threadIdx.x;
    int edge = gid >> 6;
    int lane = gid & 63;
    if (edge >= N_EDGES) return;
    int s = src[edge];
    int d = dst[edge];
    float v = emb[(size_t)s * D_FEAT + lane];
    atomicAdd(&out[(size_t)d * D_FEAT + lane], v);
    if (lane == 0) atomicAdd(&counts[d], 1.0f);
}

__global__ void gcn_norm_kernel(float* __restrict__ out,
                                const float* __restrict__ counts) {
    int i = blockIdx.x * blockDim.x + threadIdx.x;
    if (i >= N_NODES * D_FEAT) return;
    int n = i >> 6;
    float c = counts[n];
    out[i] *= (1.0f / fmaxf(c, 1.0f));
}

// ===========================================================================

extern "C" void kernel_launch(void* const* d_in, const int* in_sizes, int n_in,
                              void* d_out, int out_size, void* d_ws, size_t ws_size,
                              hipStream_t stream) {
    const float* emb = (const float*)d_in[0];
    const int*   src = (const int*)d_in[1];
    const int*   dst = (const int*)d_in[2];
    float* out = (float*)d_out;

    if (ws_size >= WS_NEEDED) {
        int* ws = (int*)d_ws;
        cur_zero_kernel<<<(NBINS * NREP + 1023) / 1024, 1024, 0, stream>>>(ws);
        rep_scatter_kernel<<<NB_SCAT, 1024, 0, stream>>>(src, dst, ws);
        fused_gather_kernel<<<NBINS, 256, 0, stream>>>(emb, ws, out);
    } else {
        float* counts = (float*)d_ws;
        gcn_zero_kernel<<<2048, 256, 0, stream>>>(out, counts);
        const int scatter_blocks = (N_EDGES * 64) / 256;
        gcn_scatter_kernel<<<scatter_blocks, 256, 0, stream>>>(emb, src, dst, out, counts);
        const int norm_blocks = (N_NODES * D_FEAT + 255) / 256;
        gcn_norm_kernel<<<norm_blocks, 256, 0, stream>>>(out, counts);
    }
}

// Round 10
// 72.342 us; speedup vs baseline: 1.4660x; 1.4660x over previous
//
#include <hip/hip_runtime.h>

#define N_NODES 100000
#define N_EDGES 1000000
#define D_FEAT  64

// Binning: 64 consecutive dst nodes per bin (R6's proven partition geometry)
#define BIN_SHIFT 6
#define BIN_NODES 64
#define NBINS ((N_NODES + BIN_NODES - 1) >> BIN_SHIFT)   // 1563
#define BIN_CAP 1536   // mean edges/bin = 640, sigma ~25 -> 35 sigma headroom

// Deterministic partition: NB_PART contiguous edge chunks, radix-style.
#define NB_PART 128
#define CHUNK ((N_EDGES + NB_PART - 1) / NB_PART)        // 7813 (< 65536 -> u16 safe)

// ---------------------------------------------------------------------------
// Workspace layout:
//   H      [NBINS][NB_PART] u16   per-(bin,chunk) histogram -> excl offsets
//   T      [NBINS] int            per-bin totals
//   BASE   [NBINS] int            exclusive scan of T
//   bucket [N_EDGES] int          packed (local_dst << 17) | src, by bin
// total ~4.4 MB
// ---------------------------------------------------------------------------
#define WS_H_INTS ((NBINS * NB_PART + 1) / 2)
#define WS_T      WS_H_INTS
#define WS_BASE   (WS_T + NBINS)
#define WS_BUCKET (WS_BASE + NBINS)
#define WS_NEEDED ((size_t)(WS_BUCKET + N_EDGES) * sizeof(int))

// KA: per-chunk histogram (LDS privatized), 1024 threads
__global__ __launch_bounds__(1024) void part_hist_kernel(const int* __restrict__ dst,
                                                         int* __restrict__ ws) {
    unsigned short* H = (unsigned short*)ws;
    __shared__ int h[NBINS];
    for (int j = threadIdx.x; j < NBINS; j += 1024) h[j] = 0;
    __syncthreads();
    int blk = blockIdx.x;
    int e0 = blk * CHUNK, e1 = min(N_EDGES, e0 + CHUNK);
    for (int e = e0 + threadIdx.x; e < e1; e += 1024)
        atomicAdd(&h[dst[e] >> BIN_SHIFT], 1);
    __syncthreads();
    for (int j = threadIdx.x; j < NBINS; j += 1024)
        H[j * NB_PART + blk] = (unsigned short)h[j];
}

// KB: per-bin exclusive scan across the 128 chunks (one wave per bin)
__global__ __launch_bounds__(256) void part_colscan_kernel(int* __restrict__ ws) {
    unsigned short* H = (unsigned short*)ws;
    int wave = threadIdx.x >> 6;
    int lane = threadIdx.x & 63;
    int j = blockIdx.x * 4 + wave;
    if (j >= NBINS) return;
    unsigned short* Hrow = H + j * NB_PART;

    int v0 = Hrow[lane];
    int incl0 = v0;
    #pragma unroll
    for (int o = 1; o < 64; o <<= 1) {
        int t = __shfl_up(incl0, o);
        if (lane >= o) incl0 += t;
    }
    int excl0 = incl0 - v0;
    int tot0 = __shfl(incl0, 63);

    int v1 = Hrow[64 + lane];
    int incl1 = v1;
    #pragma unroll
    for (int o = 1; o < 64; o <<= 1) {
        int t = __shfl_up(incl1, o);
        if (lane >= o) incl1 += t;
    }
    int excl1 = tot0 + incl1 - v1;

    Hrow[lane]      = (unsigned short)excl0;
    Hrow[64 + lane] = (unsigned short)excl1;
    if (lane == 63) ws[WS_T + j] = tot0 + incl1;
}

// KC: exclusive scan of bin totals -> BASE (LDS-staged serial wave)
__global__ __launch_bounds__(1024) void base_scan_kernel(int* __restrict__ ws) {
    const int PAD = ((NBINS + 63) / 64) * 64;
    __shared__ int sT[((NBINS + 63) / 64) * 64];
    for (int i = threadIdx.x; i < PAD; i += 1024)
        sT[i] = (i < NBINS) ? ws[WS_T + i] : 0;
    __syncthreads();
    if (threadIdx.x < 64) {
        int lane = threadIdx.x;
        int carry = 0;
        for (int c = 0; c < NBINS; c += 64) {
            int v = sT[c + lane];
            int incl = v;
            #pragma unroll
            for (int o = 1; o < 64; o <<= 1) {
                int t = __shfl_up(incl, o);
                if (lane >= o) incl += t;
            }
            if (c + lane < NBINS) ws[WS_BASE + c + lane] = carry + incl - v;
            carry += __shfl(incl, 63);
        }
    }
}

// KE: rank via LDS cursors (no global atomics), write packed edges into
// per-(chunk,bin) contiguous runs. 1024 threads.
__global__ __launch_bounds__(1024) void part_scatter_kernel(const int* __restrict__ src,
                                                            const int* __restrict__ dst,
                                                            int* __restrict__ ws) {
    unsigned short* H = (unsigned short*)ws;
    __shared__ int cur[NBINS];
    int blk = blockIdx.x;
    for (int j = threadIdx.x; j < NBINS; j += 1024)
        cur[j] = ws[WS_BASE + j] + (int)H[j * NB_PART + blk];
    __syncthreads();
    int e0 = blk * CHUNK, e1 = min(N_EDGES, e0 + CHUNK);
    for (int e = e0 + threadIdx.x; e < e1; e += 1024) {
        int d = dst[e], s = src[e];
        int j = d >> BIN_SHIFT;
        int slot = atomicAdd(&cur[j], 1);          // LDS atomic
        ws[WS_BUCKET + slot] = ((d & (BIN_NODES - 1)) << 17) | s;
    }
}

// K5: per-bin counting-sort (bucket entries register-staged across the sync)
// + float4 gather, 16 lanes/row, 4 edge-subgroups, shfl_xor reduce
// (R5's proven gather, minus the s_edges LDS array).
__global__ __launch_bounds__(256) void fused_gather_kernel(const float* __restrict__ emb,
                                                           const int* __restrict__ ws,
                                                           float* __restrict__ out) {
    __shared__ int s_sorted[BIN_CAP];
    __shared__ int s_hist[BIN_NODES];
    __shared__ int s_off[BIN_NODES];
    __shared__ int s_cur[BIN_NODES];

    int b   = blockIdx.x;
    int tid = threadIdx.x;
    int cnt  = ws[WS_T + b];
    if (cnt > BIN_CAP) cnt = BIN_CAP;   // statistically impossible; defensive
    int base = ws[WS_BASE + b];

    if (tid < BIN_NODES) s_hist[tid] = 0;
    __syncthreads();

    // register-stage bucket entries (<=6/thread) + LDS histogram
    int p[6];
    {
        const int* __restrict__ bucket = ws + WS_BUCKET + base;
        #pragma unroll
        for (int k = 0; k < 6; ++k) {
            int idx = tid + k * 256;
            p[k] = 0;
            if (idx < cnt) {
                p[k] = bucket[idx];
                atomicAdd(&s_hist[p[k] >> 17], 1);
            }
        }
    }
    __syncthreads();

    // scan 64 hist entries with wave 0
    if (tid < 64) {
        int v = s_hist[tid];
        int incl = v;
        #pragma unroll
        for (int o = 1; o < 64; o <<= 1) {
            int t = __shfl_up(incl, o);
            if (tid >= o) incl += t;
        }
        s_off[tid] = incl - v;
        s_cur[tid] = incl - v;
    }
    __syncthreads();

    // counting-sort scatter within LDS
    #pragma unroll
    for (int k = 0; k < 6; ++k) {
        int idx = tid + k * 256;
        if (idx < cnt)
            s_sorted[atomicAdd(&s_cur[p[k] >> 17], 1)] = p[k] & 0x1FFFF;
    }
    __syncthreads();

    // gather: 4 waves x 16 nodes; sub = edge slot (0..3), fq = float4 index
    int wave = tid >> 6, lane = tid & 63;
    int sub  = lane >> 4;
    int fq   = lane & 15;

    for (int ln = wave * 16; ln < wave * 16 + 16; ++ln) {
        int node = (b << BIN_SHIFT) + ln;
        if (node >= N_NODES) break;
        int deg = s_hist[ln];
        int off = s_off[ln];

        float4 acc = make_float4(0.f, 0.f, 0.f, 0.f);
        int i = sub;
        for (; i + 4 < deg; i += 8) {
            int s0 = s_sorted[off + i];
            int s1 = s_sorted[off + i + 4];
            const float4* r0 = (const float4*)(emb + (size_t)s0 * D_FEAT);
            const float4* r1 = (const float4*)(emb + (size_t)s1 * D_FEAT);
            float4 v0 = r0[fq];
            float4 v1 = r1[fq];
            acc.x += v0.x + v1.x;
            acc.y += v0.y + v1.y;
            acc.z += v0.z + v1.z;
            acc.w += v0.w + v1.w;
        }
        if (i < deg) {
            int s0 = s_sorted[off + i];
            const float4* r0 = (const float4*)(emb + (size_t)s0 * D_FEAT);
            float4 v0 = r0[fq];
            acc.x += v0.x; acc.y += v0.y; acc.z += v0.z; acc.w += v0.w;
        }

        // reduce across the 4 edge subgroups (lanes l, l^16, l^32, l^48)
        #pragma unroll
        for (int m = 16; m < 64; m <<= 1) {
            acc.x += __shfl_xor(acc.x, m);
            acc.y += __shfl_xor(acc.y, m);
            acc.z += __shfl_xor(acc.z, m);
            acc.w += __shfl_xor(acc.w, m);
        }

        if (sub == 0) {
            float inv = 1.0f / (float)max(deg, 1);
            acc.x *= inv; acc.y *= inv; acc.z *= inv; acc.w *= inv;
            *(float4*)(out + (size_t)node * D_FEAT + fq * 4) = acc;
        }
    }
}

// ======================= Fallback (R1 atomic path) =========================

__global__ void gcn_zero_kernel(float* __restrict__ out, float* __restrict__ counts) {
    int stride = gridDim.x * blockDim.x;
    int i = blockIdx.x * blockDim.x + threadIdx.x;
    const int total = N_NODES * D_FEAT;
    for (int idx = i; idx < total; idx += stride) out[idx] = 0.0f;
    for (int idx = i; idx < N_NODES; idx += stride) counts[idx] = 0.0f;
}

__global__ void gcn_scatter_kernel(const float* __restrict__ emb,
                                   const int* __restrict__ src,
                                   const int* __restrict__ dst,
                                   float* __restrict__ out,
                                   float* __restrict__ counts) {
    int gid  = blockIdx.x * blockDim.x + threadIdx.x;
    int edge = gid >> 6;
    int lane = gid & 63;
    if (edge >= N_EDGES) return;
    int s = src[edge];
    int d = dst[edge];
    float v = emb[(size_t)s * D_FEAT + lane];
    atomicAdd(&out[(size_t)d * D_FEAT + lane], v);
    if (lane == 0) atomicAdd(&counts[d], 1.0f);
}

__global__ void gcn_norm_kernel(float* __restrict__ out,
                                const float* __restrict__ counts) {
    int i = blockIdx.x * blockDim.x + threadIdx.x;
    if (i >= N_NODES * D_FEAT) return;
    int n = i >> 6;
    float c = counts[n];
    out[i] *= (1.0f / fmaxf(c, 1.0f));
}

// ===========================================================================

extern "C" void kernel_launch(void* const* d_in, const int* in_sizes, int n_in,
                              void* d_out, int out_size, void* d_ws, size_t ws_size,
                              hipStream_t stream) {
    const float* emb = (const float*)d_in[0];
    const int*   src = (const int*)d_in[1];
    const int*   dst = (const int*)d_in[2];
    float* out = (float*)d_out;

    if (ws_size >= WS_NEEDED) {
        int* ws = (int*)d_ws;
        part_hist_kernel<<<NB_PART, 1024, 0, stream>>>(dst, ws);
        part_colscan_kernel<<<(NBINS + 3) / 4, 256, 0, stream>>>(ws);
        base_scan_kernel<<<1, 1024, 0, stream>>>(ws);
        part_scatter_kernel<<<NB_PART, 1024, 0, stream>>>(src, dst, ws);
        fused_gather_kernel<<<NBINS, 256, 0, stream>>>(emb, ws, out);
    } else {
        float* counts = (float*)d_ws;
        gcn_zero_kernel<<<2048, 256, 0, stream>>>(out, counts);
        const int scatter_blocks = (N_EDGES * 64) / 256;
        gcn_scatter_kernel<<<scatter_blocks, 256, 0, stream>>>(emb, src, dst, out, counts);
        const int norm_blocks = (N_NODES * D_FEAT + 255) / 256;
        gcn_norm_kernel<<<norm_blocks, 256, 0, stream>>>(out, counts);
    }
}

// Round 11
// 70.449 us; speedup vs baseline: 1.5054x; 1.0269x over previous
//
#include <hip/hip_runtime.h>

#define N_NODES 100000
#define N_EDGES 1000000
#define D_FEAT  64

// Binning: 64 consecutive dst nodes per bin
#define BIN_SHIFT 6
#define BIN_NODES 64
#define NBINS ((N_NODES + BIN_NODES - 1) >> BIN_SHIFT)   // 1563
#define BIN_CAP 1536   // mean edges/bin = 640, sigma ~25 -> 35 sigma headroom

// Deterministic partition: NB_PART contiguous edge chunks, radix-style.
#define NB_PART 128
#define CHUNK ((N_EDGES + NB_PART - 1) / NB_PART)        // 7813 (< 65536 -> u16 safe)

// ---------------------------------------------------------------------------
// Workspace layout:
//   H      [NBINS][NB_PART] u16   per-(bin,chunk) histogram -> excl offsets
//   T      [NBINS] int            per-bin totals
//   BASE   [NBINS] int            exclusive scan of T
//   bucket [N_EDGES] int          packed (local_dst << 17) | src, by bin
// total ~4.4 MB
// ---------------------------------------------------------------------------
#define WS_H_INTS ((NBINS * NB_PART + 1) / 2)
#define WS_T      WS_H_INTS
#define WS_BASE   (WS_T + NBINS)
#define WS_BUCKET (WS_BASE + NBINS)
#define WS_NEEDED ((size_t)(WS_BUCKET + N_EDGES) * sizeof(int))

// KA: per-chunk histogram (LDS privatized), 1024 threads
__global__ __launch_bounds__(1024) void part_hist_kernel(const int* __restrict__ dst,
                                                         int* __restrict__ ws) {
    unsigned short* H = (unsigned short*)ws;
    __shared__ int h[NBINS];
    for (int j = threadIdx.x; j < NBINS; j += 1024) h[j] = 0;
    __syncthreads();
    int blk = blockIdx.x;
    int e0 = blk * CHUNK, e1 = min(N_EDGES, e0 + CHUNK);
    for (int e = e0 + threadIdx.x; e < e1; e += 1024)
        atomicAdd(&h[dst[e] >> BIN_SHIFT], 1);
    __syncthreads();
    for (int j = threadIdx.x; j < NBINS; j += 1024)
        H[j * NB_PART + blk] = (unsigned short)h[j];
}

// KB: per-bin exclusive scan across the 128 chunks (one wave per bin)
__global__ __launch_bounds__(256) void part_colscan_kernel(int* __restrict__ ws) {
    unsigned short* H = (unsigned short*)ws;
    int wave = threadIdx.x >> 6;
    int lane = threadIdx.x & 63;
    int j = blockIdx.x * 4 + wave;
    if (j >= NBINS) return;
    unsigned short* Hrow = H + j * NB_PART;

    int v0 = Hrow[lane];
    int incl0 = v0;
    #pragma unroll
    for (int o = 1; o < 64; o <<= 1) {
        int t = __shfl_up(incl0, o);
        if (lane >= o) incl0 += t;
    }
    int excl0 = incl0 - v0;
    int tot0 = __shfl(incl0, 63);

    int v1 = Hrow[64 + lane];
    int incl1 = v1;
    #pragma unroll
    for (int o = 1; o < 64; o <<= 1) {
        int t = __shfl_up(incl1, o);
        if (lane >= o) incl1 += t;
    }
    int excl1 = tot0 + incl1 - v1;

    Hrow[lane]      = (unsigned short)excl0;
    Hrow[64 + lane] = (unsigned short)excl1;
    if (lane == 63) ws[WS_T + j] = tot0 + incl1;
}

// KC: exclusive scan of bin totals -> BASE (LDS-staged serial wave)
__global__ __launch_bounds__(1024) void base_scan_kernel(int* __restrict__ ws) {
    const int PAD = ((NBINS + 63) / 64) * 64;
    __shared__ int sT[((NBINS + 63) / 64) * 64];
    for (int i = threadIdx.x; i < PAD; i += 1024)
        sT[i] = (i < NBINS) ? ws[WS_T + i] : 0;
    __syncthreads();
    if (threadIdx.x < 64) {
        int lane = threadIdx.x;
        int carry = 0;
        for (int c = 0; c < NBINS; c += 64) {
            int v = sT[c + lane];
            int incl = v;
            #pragma unroll
            for (int o = 1; o < 64; o <<= 1) {
                int t = __shfl_up(incl, o);
                if (lane >= o) incl += t;
            }
            if (c + lane < NBINS) ws[WS_BASE + c + lane] = carry + incl - v;
            carry += __shfl(incl, 63);
        }
    }
}

// KE: rank via LDS cursors (no global atomics), write packed edges into
// per-(chunk,bin) contiguous runs. 1024 threads.
__global__ __launch_bounds__(1024) void part_scatter_kernel(const int* __restrict__ src,
                                                            const int* __restrict__ dst,
                                                            int* __restrict__ ws) {
    unsigned short* H = (unsigned short*)ws;
    __shared__ int cur[NBINS];
    int blk = blockIdx.x;
    for (int j = threadIdx.x; j < NBINS; j += 1024)
        cur[j] = ws[WS_BASE + j] + (int)H[j * NB_PART + blk];
    __syncthreads();
    int e0 = blk * CHUNK, e1 = min(N_EDGES, e0 + CHUNK);
    for (int e = e0 + threadIdx.x; e < e1; e += 1024) {
        int d = dst[e], s = src[e];
        int j = d >> BIN_SHIFT;
        int slot = atomicAdd(&cur[j], 1);          // LDS atomic
        ws[WS_BUCKET + slot] = ((d & (BIN_NODES - 1)) << 17) | s;
    }
}

// K5: per-bin counting-sort + float4 gather. 512 threads = 8 waves x 8 nodes.
// Inner loop prefetch-pipelined: main iter issues 4 independent row loads;
// tail issues up to 3 guarded loads before any use.
__global__ __launch_bounds__(512) void fused_gather_kernel(const float* __restrict__ emb,
                                                           const int* __restrict__ ws,
                                                           float* __restrict__ out) {
    __shared__ int s_sorted[BIN_CAP];
    __shared__ int s_hist[BIN_NODES];
    __shared__ int s_off[BIN_NODES];
    __shared__ int s_cur[BIN_NODES];

    int b   = blockIdx.x;
    int tid = threadIdx.x;
    int cnt  = ws[WS_T + b];
    if (cnt > BIN_CAP) cnt = BIN_CAP;   // statistically impossible; defensive
    int base = ws[WS_BASE + b];

    if (tid < BIN_NODES) s_hist[tid] = 0;
    __syncthreads();

    // register-stage bucket entries (<=3/thread) + LDS histogram
    int p0 = 0, p1 = 0, p2 = 0;
    {
        const int* __restrict__ bucket = ws + WS_BUCKET + base;
        if (tid < cnt)        { p0 = bucket[tid];        atomicAdd(&s_hist[p0 >> 17], 1); }
        if (tid + 512 < cnt)  { p1 = bucket[tid + 512];  atomicAdd(&s_hist[p1 >> 17], 1); }
        if (tid + 1024 < cnt) { p2 = bucket[tid + 1024]; atomicAdd(&s_hist[p2 >> 17], 1); }
    }
    __syncthreads();

    // scan 64 hist entries with wave 0
    if (tid < 64) {
        int v = s_hist[tid];
        int incl = v;
        #pragma unroll
        for (int o = 1; o < 64; o <<= 1) {
            int t = __shfl_up(incl, o);
            if (tid >= o) incl += t;
        }
        s_off[tid] = incl - v;
        s_cur[tid] = incl - v;
    }
    __syncthreads();

    // counting-sort scatter within LDS
    if (tid < cnt)        s_sorted[atomicAdd(&s_cur[p0 >> 17], 1)] = p0 & 0x1FFFF;
    if (tid + 512 < cnt)  s_sorted[atomicAdd(&s_cur[p1 >> 17], 1)] = p1 & 0x1FFFF;
    if (tid + 1024 < cnt) s_sorted[atomicAdd(&s_cur[p2 >> 17], 1)] = p2 & 0x1FFFF;
    __syncthreads();

    // gather: 8 waves x 8 nodes; sub = edge slot (0..3), fq = float4 index
    int wave = tid >> 6, lane = tid & 63;
    int sub  = lane >> 4;
    int fq   = lane & 15;

    for (int ln = wave * 8; ln < wave * 8 + 8; ++ln) {
        int node = (b << BIN_SHIFT) + ln;
        if (node >= N_NODES) break;
        int deg = s_hist[ln];
        int off = s_off[ln];

        float4 acc = make_float4(0.f, 0.f, 0.f, 0.f);
        int i = sub;
        // main: 4 rows in flight
        for (; i + 12 < deg; i += 16) {
            int s0 = s_sorted[off + i];
            int s1 = s_sorted[off + i + 4];
            int s2 = s_sorted[off + i + 8];
            int s3 = s_sorted[off + i + 12];
            float4 v0 = ((const float4*)(emb + (size_t)s0 * D_FEAT))[fq];
            float4 v1 = ((const float4*)(emb + (size_t)s1 * D_FEAT))[fq];
            float4 v2 = ((const float4*)(emb + (size_t)s2 * D_FEAT))[fq];
            float4 v3 = ((const float4*)(emb + (size_t)s3 * D_FEAT))[fq];
            acc.x += v0.x + v1.x + v2.x + v3.x;
            acc.y += v0.y + v1.y + v2.y + v3.y;
            acc.z += v0.z + v1.z + v2.z + v3.z;
            acc.w += v0.w + v1.w + v2.w + v3.w;
        }
        // tail: up to 3 guarded loads, all issued before use
        {
            float4 v0 = make_float4(0.f, 0.f, 0.f, 0.f);
            float4 v1 = make_float4(0.f, 0.f, 0.f, 0.f);
            float4 v2 = make_float4(0.f, 0.f, 0.f, 0.f);
            if (i < deg)     v0 = ((const float4*)(emb + (size_t)s_sorted[off + i]      * D_FEAT))[fq];
            if (i + 4 < deg) v1 = ((const float4*)(emb + (size_t)s_sorted[off + i + 4]  * D_FEAT))[fq];
            if (i + 8 < deg) v2 = ((const float4*)(emb + (size_t)s_sorted[off + i + 8]  * D_FEAT))[fq];
            acc.x += v0.x + v1.x + v2.x;
            acc.y += v0.y + v1.y + v2.y;
            acc.z += v0.z + v1.z + v2.z;
            acc.w += v0.w + v1.w + v2.w;
        }

        // reduce across the 4 edge subgroups (lanes l, l^16, l^32, l^48)
        #pragma unroll
        for (int m = 16; m < 64; m <<= 1) {
            acc.x += __shfl_xor(acc.x, m);
            acc.y += __shfl_xor(acc.y, m);
            acc.z += __shfl_xor(acc.z, m);
            acc.w += __shfl_xor(acc.w, m);
        }

        if (sub == 0) {
            float inv = 1.0f / (float)max(deg, 1);
            acc.x *= inv; acc.y *= inv; acc.z *= inv; acc.w *= inv;
            *(float4*)(out + (size_t)node * D_FEAT + fq * 4) = acc;
        }
    }
}

// ======================= Fallback (R1 atomic path) =========================

__global__ void gcn_zero_kernel(float* __restrict__ out, float* __restrict__ counts) {
    int stride = gridDim.x * blockDim.x;
    int i = blockIdx.x * blockDim.x + threadIdx.x;
    const int total = N_NODES * D_FEAT;
    for (int idx = i; idx < total; idx += stride) out[idx] = 0.0f;
    for (int idx = i; idx < N_NODES; idx += stride) counts[idx] = 0.0f;
}

__global__ void gcn_scatter_kernel(const float* __restrict__ emb,
                                   const int* __restrict__ src,
                                   const int* __restrict__ dst,
                                   float* __restrict__ out,
                                   float* __restrict__ counts) {
    int gid  = blockIdx.x * blockDim.x + threadIdx.x;
    int edge = gid >> 6;
    int lane = gid & 63;
    if (edge >= N_EDGES) return;
    int s = src[edge];
    int d = dst[edge];
    float v = emb[(size_t)s * D_FEAT + lane];
    atomicAdd(&out[(size_t)d * D_FEAT + lane], v);
    if (lane == 0) atomicAdd(&counts[d], 1.0f);
}

__global__ void gcn_norm_kernel(float* __restrict__ out,
                                const float* __restrict__ counts) {
    int i = blockIdx.x * blockDim.x + threadIdx.x;
    if (i >= N_NODES * D_FEAT) return;
    int n = i >> 6;
    float c = counts[n];
    out[i] *= (1.0f / fmaxf(c, 1.0f));
}

// ===========================================================================

extern "C" void kernel_launch(void* const* d_in, const int* in_sizes, int n_in,
                              void* d_out, int out_size, void* d_ws, size_t ws_size,
                              hipStream_t stream) {
    const float* emb = (const float*)d_in[0];
    const int*   src = (const int*)d_in[1];
    const int*   dst = (const int*)d_in[2];
    float* out = (float*)d_out;

    if (ws_size >= WS_NEEDED) {
        int* ws = (int*)d_ws;
        part_hist_kernel<<<NB_PART, 1024, 0, stream>>>(dst, ws);
        part_colscan_kernel<<<(NBINS + 3) / 4, 256, 0, stream>>>(ws);
        base_scan_kernel<<<1, 1024, 0, stream>>>(ws);
        part_scatter_kernel<<<NB_PART, 1024, 0, stream>>>(src, dst, ws);
        fused_gather_kernel<<<NBINS, 512, 0, stream>>>(emb, ws, out);
    } else {
        float* counts = (float*)d_ws;
        gcn_zero_kernel<<<2048, 256, 0, stream>>>(out, counts);
        const int scatter_blocks = (N_EDGES * 64) / 256;
        gcn_scatter_kernel<<<scatter_blocks, 256, 0, stream>>>(emb, src, dst, out, counts);
        const int norm_blocks = (N_NODES * D_FEAT + 255) / 256;
        gcn_norm_kernel<<<norm_blocks, 256, 0, stream>>>(out, counts);
    }
}